// Round 1
// baseline (592.856 us; speedup 1.0000x reference)
//
#include <hip/hip_runtime.h>
#include <hip/hip_bf16.h>

// Problem constants (from reference)
#define NN 50000
#define EE 1600000
#define DIN 128

#define BKT_SHIFT 6                       // 64 nodes per bucket
#define NB ((NN + 63) >> 6)               // 782 buckets
#define BSLACK 2688                       // slack slots per bucket (mean 2110, +12.5 sigma)
#define CHUNK 4096                        // edges per binning workgroup (16/thread)
#define ZOUT (NN * 16 / 4)                // float4 slots to zero in d_out

typedef _Float16 half_t;
typedef __attribute__((ext_vector_type(2))) _Float16 half2_t;
typedef __attribute__((ext_vector_type(4))) _Float16 half4_t;
typedef __attribute__((ext_vector_type(8))) _Float16 half8_t;
typedef __attribute__((ext_vector_type(4))) float float4_t;

// ---------------------------------------------------------------------------
// prep: build extended B^T hi/lo for each layer (W^T plus a 16-wide folded
// score tile: cols j<8 = ss head j, j>=8 = ds head j-8), zero gcursor, and
// zero d_out (layer-3 head-pair blocks atomically accumulate into it).
// ---------------------------------------------------------------------------
__device__ __forceinline__ void split_write(half_t* __restrict__ bh, half_t* __restrict__ bl,
                                            int idx, float v) {
    half_t h = (half_t)v;
    bh[idx] = h;
    bl[idx] = (half_t)(v - (float)h);
}

__device__ __forceinline__ void build_bt(const float* __restrict__ W,
                                         const float* __restrict__ as,
                                         const float* __restrict__ ad,
                                         half_t* __restrict__ Bh, half_t* __restrict__ Bl,
                                         int elem, int NCOL, int H) {
    int r = elem >> 7, k = elem & 127;  // Bt row r (out col / score), k in 0..127
    float v;
    if (r < NCOL) {
        v = W[k * NCOL + r];
    } else {
        int j = r - NCOL;
        v = 0.f;
        if (j < 8) {
            if (j < H) {
                float s = 0.f;
#pragma unroll
                for (int f = 0; f < 16; ++f) s += W[k * NCOL + j * 16 + f] * as[j * 16 + f];
                v = s;
            }
        } else {
            int hh = j - 8;
            if (hh < H) {
                float s = 0.f;
#pragma unroll
                for (int f = 0; f < 16; ++f) s += W[k * NCOL + hh * 16 + f] * ad[hh * 16 + f];
                v = s;
            }
        }
    }
    split_write(Bh, Bl, r * 128 + k, v);
}

#define T1 (144 * 128)
#define T3 (80 * 128)
__global__ __launch_bounds__(256) void prep_kernel(
    const float* __restrict__ W1, const float* __restrict__ W2, const float* __restrict__ W3,
    const float* __restrict__ as1, const float* __restrict__ ad1,
    const float* __restrict__ as2, const float* __restrict__ ad2,
    const float* __restrict__ as3, const float* __restrict__ ad3,
    half_t* __restrict__ B1h, half_t* __restrict__ B1l,
    half_t* __restrict__ B2h, half_t* __restrict__ B2l,
    half_t* __restrict__ B3h, half_t* __restrict__ B3l,
    int* __restrict__ gcursor, float* __restrict__ dout) {
    int id = blockIdx.x * 256 + threadIdx.x;
    if (id < T1) {
        build_bt(W1, as1, ad1, B1h, B1l, id, 128, 8);
    } else if (id < 2 * T1) {
        build_bt(W2, as2, ad2, B2h, B2l, id - T1, 128, 8);
    } else if (id < 2 * T1 + T3) {
        build_bt(W3, as3, ad3, B3h, B3l, id - 2 * T1, 64, 4);
    } else {
        int i = id - (2 * T1 + T3);
        if (i < NB) {
            gcursor[i] = 0;
        } else {
            int z = i - NB;
            if (z < ZOUT) ((float4*)dout)[z] = make_float4(0.f, 0.f, 0.f, 0.f);
        }
    }
}

// ---------------------------------------------------------------------------
// CSR build (r9-proven): bucket binning -> per-bucket fine scatter into
// bucket-slack-layout csr with per-node begin/end. Packed src*64+dloc.
// ---------------------------------------------------------------------------
__global__ __launch_bounds__(256) void bin_kernel(const int* __restrict__ A,
                                                  int* __restrict__ gcursor,
                                                  int* __restrict__ binned, int e, int n) {
    __shared__ int lcount[NB];
    __shared__ int lbase[NB];
    int chunk0 = blockIdx.x * CHUNK;
    int cend = chunk0 + CHUNK;
    if (cend > e + n) cend = e + n;
    for (int i = threadIdx.x; i < NB; i += 256) lcount[i] = 0;
    __syncthreads();
    int sreg[16], dreg[16];
#pragma unroll
    for (int l = 0; l < 16; ++l) {
        int i = chunk0 + l * 256 + threadIdx.x;
        if (i < cend) {
            if (i < e) { sreg[l] = A[i]; dreg[l] = A[e + i]; }
            else       { sreg[l] = dreg[l] = i - e; }
            atomicAdd(&lcount[dreg[l] >> BKT_SHIFT], 1);
        } else {
            dreg[l] = -1;
        }
    }
    __syncthreads();
    for (int b = threadIdx.x; b < NB; b += 256) {
        int c = lcount[b];
        lbase[b] = c ? atomicAdd(&gcursor[b], c) : 0;
        lcount[b] = 0;
    }
    __syncthreads();
#pragma unroll
    for (int l = 0; l < 16; ++l) {
        if (dreg[l] >= 0) {
            int bkt = dreg[l] >> BKT_SHIFT;
            int pos = lbase[bkt] + atomicAdd(&lcount[bkt], 1);
            if (pos < BSLACK)
                binned[(size_t)bkt * BSLACK + pos] = (sreg[l] << 6) | (dreg[l] & 63);
        }
    }
}

__global__ __launch_bounds__(256) void fine_scatter(const int* __restrict__ binned,
                                                    const int* __restrict__ gcursor,
                                                    int* __restrict__ begE,
                                                    int* __restrict__ endE,
                                                    int* __restrict__ csr) {
    __shared__ int lc[64];
    __shared__ int scur[64];
    int b = blockIdx.x;
    int node0 = b << BKT_SHIFT;
    int cnt = gcursor[b];
    if (cnt > BSLACK) cnt = BSLACK;
    const int* bp = binned + (size_t)b * BSLACK;
    if (threadIdx.x < 64) lc[threadIdx.x] = 0;
    __syncthreads();
    for (int j = threadIdx.x; j < cnt; j += 256) atomicAdd(&lc[bp[j] & 63], 1);
    __syncthreads();
    if (threadIdx.x < 64) {  // wave-parallel exclusive scan over 64 counts
        int lane = threadIdx.x;
        int c = lc[lane];
        int v = c;
#pragma unroll
        for (int off = 1; off < 64; off <<= 1) {
            int u = __shfl_up(v, off, 64);
            if (lane >= off) v += u;
        }
        int begin = b * BSLACK + v - c;  // bucket-local slack layout
        scur[lane] = begin;
        int node = node0 + lane;
        if (node < NN) {
            begE[node] = begin;
            endE[node] = begin + c;
        }
    }
    __syncthreads();
    for (int j = threadIdx.x; j < cnt; j += 256) {
        int v = bp[j];
        int pos = atomicAdd(&scur[v & 63], 1);
        csr[pos] = v >> 6;
    }
}

// ---------------------------------------------------------------------------
// Split-fp16 MFMA GEMM, LDS-staged B in fragment order (unchanged main loop).
// NEW epilogue: C16 is written HEAD-MAJOR  (C16[h][row][16])  and ss/ds are
// written head-major (ss[h][row]) so the aggregation pass can partition by
// head-pair and keep its gather table L2-resident.
// ---------------------------------------------------------------------------
template <int NTC, int H, bool A32>
__global__ __launch_bounds__(256) void gemm_mfma(
    const float* __restrict__ X32,
    const half_t* __restrict__ Ah, const half_t* __restrict__ Al,
    const half_t* __restrict__ Bth, const half_t* __restrict__ Btl,
    half_t* __restrict__ C16, float* __restrict__ ss, float* __restrict__ ds, int M) {
    constexpr int NCOL = NTC * 16;
    constexpr int NR = NTC + 1;               // tiles incl. score tile
    constexpr int NCHUNK = NR * 256;          // 16B chunks per B array
    __shared__ __align__(16) half_t Bs[2][NR * 2048];  // 73.7 KB (NTC=8)
    int tid = threadIdx.x;
    int w = tid >> 6, lane = tid & 63;
    int m = lane & 15, q = lane >> 4;
    int row0 = blockIdx.x * 64 + w * 16;

    // cooperative fragment-ordered B load (each thread NR chunks per array)
    for (int P = tid; P < NCHUNK; P += 256) {
        int nt = P >> 8, k0 = (P >> 6) & 3, qq = (P >> 4) & 3, mm = P & 15;
        int src = (nt * 16 + mm) * 128 + qq * 8 + k0 * 32;  // half index
        *(half8_t*)&Bs[0][(size_t)P * 8] = *(const half8_t*)&Bth[src];
        *(half8_t*)&Bs[1][(size_t)P * 8] = *(const half8_t*)&Btl[src];
    }

    // A fragment (VMEM, per-wave) — overlaps the barrier
    int ar = row0 + m;
    if (ar >= M) ar = M - 1;  // clamp (stores are guarded)
    half8_t ahf[4], alf[4];
    if constexpr (A32) {
        const float* px = X32 + (size_t)ar * 128 + q * 8;
#pragma unroll
        for (int k0 = 0; k0 < 4; ++k0) {
            float4 u0 = *(const float4*)(px + k0 * 32);
            float4 u1 = *(const float4*)(px + k0 * 32 + 4);
            float uv[8] = {u0.x, u0.y, u0.z, u0.w, u1.x, u1.y, u1.z, u1.w};
#pragma unroll
            for (int j = 0; j < 8; ++j) {
                half_t h = (half_t)uv[j];
                ahf[k0][j] = h;
                alf[k0][j] = (half_t)(uv[j] - (float)h);
            }
        }
    } else {
        const half_t* pa = Ah + (size_t)ar * 128 + q * 8;
        const half_t* pl = Al + (size_t)ar * 128 + q * 8;
#pragma unroll
        for (int k0 = 0; k0 < 4; ++k0) {
            ahf[k0] = *(const half8_t*)(pa + k0 * 32);
            alf[k0] = *(const half8_t*)(pl + k0 * 32);
        }
    }

    __syncthreads();

    float4_t acc[NR];
#pragma unroll
    for (int nt = 0; nt < NR; ++nt) {
        acc[nt][0] = 0.f; acc[nt][1] = 0.f; acc[nt][2] = 0.f; acc[nt][3] = 0.f;
    }

#pragma unroll
    for (int nt = 0; nt < NR; ++nt) {
#pragma unroll
        for (int k0 = 0; k0 < 4; ++k0) {
            half8_t bh = *(const half8_t*)&Bs[0][(size_t)((nt * 4 + k0) * 64 + lane) * 8];
            half8_t bl = *(const half8_t*)&Bs[1][(size_t)((nt * 4 + k0) * 64 + lane) * 8];
            acc[nt] = __builtin_amdgcn_mfma_f32_16x16x32_f16(ahf[k0], bh, acc[nt], 0, 0, 0);
            acc[nt] = __builtin_amdgcn_mfma_f32_16x16x32_f16(ahf[k0], bl, acc[nt], 0, 0, 0);
            acc[nt] = __builtin_amdgcn_mfma_f32_16x16x32_f16(alf[k0], bh, acc[nt], 0, 0, 0);
        }
    }

    // ss/ds head-major straight from the score tile's D layout (col=m, row=q*4+r)
#pragma unroll
    for (int r = 0; r < 4; ++r) {
        int grow = row0 + q * 4 + r;
        if (grow < M) {
            float v = acc[NTC][r];
            if (m < H) ss[(size_t)m * M + grow] = v;
            else if (m >= 8 && m < 8 + H) ds[(size_t)(m - 8) * M + grow] = v;
        }
    }

    // C16 head-major store: reuse the B LDS region as transpose bounce.
    // cs rows padded +8 halfs so the per-head column read is <=4-way banked.
    __syncthreads();
    constexpr int LDC = NCOL + 8;
    half_t* cs = (half_t*)Bs;  // [4 waves][16 rows][LDC] strips, per-wave disjoint
#pragma unroll
    for (int nt = 0; nt < NTC; ++nt)
#pragma unroll
        for (int r = 0; r < 4; ++r)
            cs[(size_t)(w * 16 + q * 4 + r) * LDC + nt * 16 + m] = (half_t)acc[nt][r];
    // copy out: per pass two heads; each 32-lane half writes one head's
    // 16 rows x 32 B = 512 B contiguous run.
    int head2 = lane >> 5, rr = (lane >> 1) & 15, hf8 = lane & 1;
    int growc = row0 + rr;
#pragma unroll
    for (int p = 0; p < NTC / 2; ++p) {
        int head = p * 2 + head2;
        half8_t v = *(const half8_t*)&cs[(size_t)(w * 16 + rr) * LDC + head * 16 + hf8 * 8];
        if (growc < M)
            *(half8_t*)(C16 + ((size_t)head * M + growc) * 16 + hf8 * 8) = v;
    }
}

// ---------------------------------------------------------------------------
// Head-pair-partitioned aggregation. Each block handles ONE head-pair over 16
// nodes (4 waves x 4 nodes); blocks ordered pair-major so each pair's 2x1.6MB
// h tables stay L2-resident on every XCD while that pair's chunk executes.
// Per node: 16 lanes = 4 edge streams x (2 heads x 2 feature-halves).
// Per edge per lane: 16 B h gather + 4 B ss gather + nontemporal csr load.
// Layers 1-2: hi/lo fp16 outputs node-major (gemm A layout). Layer 3 (MEAN):
// each pair block atomically adds its per-head-normalized half into d_out.
// ---------------------------------------------------------------------------
template <int H, bool MEAN, bool RELU>
__global__ __launch_bounds__(256) void aggregate_hs(
    const half_t* __restrict__ h, const float* __restrict__ ss,
    const float* __restrict__ dsa, const int* __restrict__ csr,
    const int* __restrict__ begE, const int* __restrict__ endE,
    const float* __restrict__ bias, half_t* __restrict__ outh,
    half_t* __restrict__ outl, float* __restrict__ out, int n, int groups) {
    int pair = blockIdx.x / groups;       // pair-major: contiguous chunk per pair
    int g = blockIdx.x - pair * groups;
    int lane = threadIdx.x & 63;
    int node = g * 16 + ((threadIdx.x >> 6) << 2) + (lane >> 4);
    if (node >= n) return;                // uniform per 16-lane group
    int ql = lane & 15;
    int stream = ql >> 2, hh = (ql >> 1) & 1, half = ql & 1;
    int head = pair * 2 + hh;
    const half_t* ht = h + (size_t)head * n * 16 + half * 8;
    const float* ssh = ss + (size_t)head * n;
    float dsc = dsa[(size_t)head * n + node];
    int begin = begE[node], end = endE[node];

    float ssum = 0.f;
    float acc[8];
#pragma unroll
    for (int k = 0; k < 8; ++k) acc[k] = 0.f;

    int j = begin + stream;               // stream's edges: j, j+4, j+8, ...
    for (; j + 12 < end; j += 16) {       // 4 edges per iteration
        int s0 = __builtin_nontemporal_load(&csr[j]);
        int s1 = __builtin_nontemporal_load(&csr[j + 4]);
        int s2 = __builtin_nontemporal_load(&csr[j + 8]);
        int s3 = __builtin_nontemporal_load(&csr[j + 12]);
        float e0 = ssh[s0], e1 = ssh[s1], e2 = ssh[s2], e3 = ssh[s3];
        half8_t t0 = *(const half8_t*)(ht + (size_t)s0 * 16);
        half8_t t1 = *(const half8_t*)(ht + (size_t)s1 * 16);
        half8_t t2 = *(const half8_t*)(ht + (size_t)s2 * 16);
        half8_t t3 = *(const half8_t*)(ht + (size_t)s3 * 16);
        e0 += dsc; e1 += dsc; e2 += dsc; e3 += dsc;
        e0 = fmaxf(e0, 0.2f * e0); e1 = fmaxf(e1, 0.2f * e1);   // leaky relu
        e2 = fmaxf(e2, 0.2f * e2); e3 = fmaxf(e3, 0.2f * e3);
        float x0 = __expf(e0), x1 = __expf(e1), x2 = __expf(e2), x3 = __expf(e3);
        ssum += (x0 + x1) + (x2 + x3);
#pragma unroll
        for (int k = 0; k < 8; ++k) {
            acc[k] = fmaf(x0, (float)t0[k], acc[k]);
            acc[k] = fmaf(x1, (float)t1[k], acc[k]);
            acc[k] = fmaf(x2, (float)t2[k], acc[k]);
            acc[k] = fmaf(x3, (float)t3[k], acc[k]);
        }
    }
    for (; j + 4 < end; j += 8) {         // 2 edges
        int s0 = __builtin_nontemporal_load(&csr[j]);
        int s1 = __builtin_nontemporal_load(&csr[j + 4]);
        float e0 = ssh[s0], e1 = ssh[s1];
        half8_t t0 = *(const half8_t*)(ht + (size_t)s0 * 16);
        half8_t t1 = *(const half8_t*)(ht + (size_t)s1 * 16);
        e0 += dsc; e1 += dsc;
        e0 = fmaxf(e0, 0.2f * e0); e1 = fmaxf(e1, 0.2f * e1);
        float x0 = __expf(e0), x1 = __expf(e1);
        ssum += x0 + x1;
#pragma unroll
        for (int k = 0; k < 8; ++k) {
            acc[k] = fmaf(x0, (float)t0[k], acc[k]);
            acc[k] = fmaf(x1, (float)t1[k], acc[k]);
        }
    }
    for (; j < end; j += 4) {             // tail: at most one edge per stream
        int s0 = __builtin_nontemporal_load(&csr[j]);
        float e0 = ssh[s0] + dsc;
        half8_t t0 = *(const half8_t*)(ht + (size_t)s0 * 16);
        e0 = fmaxf(e0, 0.2f * e0);
        float x0 = __expf(e0);
        ssum += x0;
#pragma unroll
        for (int k = 0; k < 8; ++k) acc[k] = fmaf(x0, (float)t0[k], acc[k]);
    }

    // reduce across the 4 streams (ql bits 2-3); (hh,half) preserved
    ssum += __shfl_xor(ssum, 4, 64);
    ssum += __shfl_xor(ssum, 8, 64);
#pragma unroll
    for (int k = 0; k < 8; ++k) {
        acc[k] += __shfl_xor(acc[k], 4, 64);
        acc[k] += __shfl_xor(acc[k], 8, 64);
    }
    float inv = 1.f / (ssum + 1e-16f);

    if constexpr (!MEAN) {
        if (ql < 4) {  // one lane per (hh,half): 4 x 16 B = 64 B per node
            half8_t hv, lv;
#pragma unroll
            for (int k = 0; k < 8; ++k) {
                float t = acc[k] * inv + bias[head * 16 + half * 8 + k];
                if (RELU) t = fmaxf(t, 0.f);
                hv[k] = (half_t)t;
                lv[k] = (half_t)(t - (float)hv[k]);
            }
            size_t off = (size_t)node * (H * 16) + head * 16 + half * 8;
            *(half8_t*)(outh + off) = hv;
            *(half8_t*)(outl + off) = lv;
        }
    } else {
        // per-head normalize, mean over the pair's 2 heads, atomic into d_out.
        // bias*0.5 added by both pair blocks -> full bias.
        float v[8];
#pragma unroll
        for (int k = 0; k < 8; ++k) {
            float t = acc[k] * inv;
            t += __shfl_xor(t, 2, 64);    // add the other head of this pair
            v[k] = t * 0.25f + bias[half * 8 + k] * 0.5f;
        }
        if (ql < 2) {
#pragma unroll
            for (int k = 0; k < 8; ++k)
                atomicAdd(out + (size_t)node * 16 + half * 8 + k, v[k]);
        }
    }
}

// ---------------------------------------------------------------------------
extern "C" void kernel_launch(void* const* d_in, const int* in_sizes, int n_in,
                              void* d_out, int out_size, void* d_ws, size_t ws_size,
                              hipStream_t stream) {
    const float* X  = (const float*)d_in[0];
    const int*   A  = (const int*)d_in[1];
    const float* W1 = (const float*)d_in[2];
    const float* as1 = (const float*)d_in[3];
    const float* ad1 = (const float*)d_in[4];
    const float* b1  = (const float*)d_in[5];
    const float* W2 = (const float*)d_in[6];
    const float* as2 = (const float*)d_in[7];
    const float* ad2 = (const float*)d_in[8];
    const float* b2  = (const float*)d_in[9];
    const float* W3 = (const float*)d_in[10];
    const float* as3 = (const float*)d_in[11];
    const float* ad3 = (const float*)d_in[12];
    const float* b3  = (const float*)d_in[13];

    const int N = NN, E = EE;
    const int Etot = E + N;

    char* p = (char*)d_ws;
    auto take = [&](size_t bytes) {
        char* r = p;
        p += (bytes + 255) & ~(size_t)255;
        return (void*)r;
    };
    half_t* C16   = (half_t*)take((size_t)N * 128 * 2);  // head-major h tables
    half_t* Ph    = (half_t*)take((size_t)N * 128 * 2);  // layer-1/2 activations hi
    half_t* Pl    = (half_t*)take((size_t)N * 128 * 2);  // layer-1/2 activations lo
    float* ssb    = (float*)take((size_t)N * 8 * 4);     // head-major [8][N]
    float* dsb    = (float*)take((size_t)N * 8 * 4);     // head-major [8][N]
    int* begE     = (int*)take((size_t)N * 4);
    int* endE     = (int*)take((size_t)N * 4);
    int* gcursor  = (int*)take((size_t)NB * 4);
    int* csr      = (int*)take((size_t)NB * BSLACK * 4); // slack layout, 8.4 MB
    half_t* B1h   = (half_t*)take(144 * 128 * 2);
    half_t* B1l   = (half_t*)take(144 * 128 * 2);
    half_t* B2h   = (half_t*)take(144 * 128 * 2);
    half_t* B2l   = (half_t*)take(144 * 128 * 2);
    half_t* B3h   = (half_t*)take(80 * 128 * 2);
    half_t* B3l   = (half_t*)take(80 * 128 * 2);
    // binned slack regions alias Ph (8.4 MB < 12.8 MB); Ph is dead until the
    // layer-1 aggregate, which runs strictly after fine_scatter.
    int* binned   = (int*)Ph;

    // --- prep (W^T hi/lo + folded score cols, gcursor zero, d_out zero) ---
    const int prepTotal = 2 * T1 + T3 + NB + ZOUT;
    prep_kernel<<<(prepTotal + 255) / 256, 256, 0, stream>>>(
        W1, W2, W3, as1, ad1, as2, ad2, as3, ad3,
        B1h, B1l, B2h, B2l, B3h, B3l, gcursor, (float*)d_out);
    bin_kernel<<<(Etot + CHUNK - 1) / CHUNK, 256, 0, stream>>>(A, gcursor, binned, E, N);
    fine_scatter<<<NB, 256, 0, stream>>>(binned, gcursor, begE, endE, csr);

    const int gemmRows = (N + 63) / 64;
    const int aggGroups = (N + 15) / 16;   // 3125 (exact: 3125*16 == 50000)

    // --- layer 1 (A = X fp32, split in-kernel) ---
    gemm_mfma<8, 8, true><<<gemmRows, 256, 0, stream>>>(X, nullptr, nullptr,
                                                        B1h, B1l, C16, ssb, dsb, N);
    aggregate_hs<8, false, true><<<aggGroups * 4, 256, 0, stream>>>(
        C16, ssb, dsb, csr, begE, endE, b1, Ph, Pl, nullptr, N, aggGroups);

    // --- layer 2 (agg writes back over Ph/Pl, dead after gemm2 reads them) ---
    gemm_mfma<8, 8, false><<<gemmRows, 256, 0, stream>>>(nullptr, Ph, Pl,
                                                         B2h, B2l, C16, ssb, dsb, N);
    aggregate_hs<8, false, true><<<aggGroups * 4, 256, 0, stream>>>(
        C16, ssb, dsb, csr, begE, endE, b2, Ph, Pl, nullptr, N, aggGroups);

    // --- layer 3 (H=4, per-head softmax, mean over heads via pair atomics) ---
    gemm_mfma<4, 4, false><<<gemmRows, 256, 0, stream>>>(nullptr, Ph, Pl,
                                                         B3h, B3l, C16, ssb, dsb, N);
    aggregate_hs<4, true, false><<<aggGroups * 2, 256, 0, stream>>>(
        C16, ssb, dsb, csr, begE, endE, b3, nullptr, nullptr, (float*)d_out, N, aggGroups);
}

// Round 2
// 464.170 us; speedup vs baseline: 1.2772x; 1.2772x over previous
//
#include <hip/hip_runtime.h>
#include <hip/hip_bf16.h>

// Problem constants (from reference)
#define NN 50000
#define EE 1600000
#define DIN 128

#define BKT_SHIFT 6                       // 64 nodes per bucket
#define NB ((NN + 63) >> 6)               // 782 buckets
#define BSLACK 2688                       // slack slots per bucket (mean 2110, +12.5 sigma)
#define CHUNK 4096                        // edges per binning workgroup (16/thread)
#define ZOUT (NN * 16 / 4)                // float4 slots to zero in d_out

typedef _Float16 half_t;
typedef __attribute__((ext_vector_type(2))) _Float16 half2_t;
typedef __attribute__((ext_vector_type(4))) _Float16 half4_t;
typedef __attribute__((ext_vector_type(8))) _Float16 half8_t;
typedef __attribute__((ext_vector_type(4))) float float4_t;

// ---------------------------------------------------------------------------
// prep: build extended B^T hi/lo for each layer (W^T plus a 16-wide folded
// score tile: cols j<8 = ss head j, j>=8 = ds head j-8), zero gcursor, and
// zero d_out (layer-3 head-pair blocks atomically accumulate into it).
// ---------------------------------------------------------------------------
__device__ __forceinline__ void split_write(half_t* __restrict__ bh, half_t* __restrict__ bl,
                                            int idx, float v) {
    half_t h = (half_t)v;
    bh[idx] = h;
    bl[idx] = (half_t)(v - (float)h);
}

__device__ __forceinline__ void build_bt(const float* __restrict__ W,
                                         const float* __restrict__ as,
                                         const float* __restrict__ ad,
                                         half_t* __restrict__ Bh, half_t* __restrict__ Bl,
                                         int elem, int NCOL, int H) {
    int r = elem >> 7, k = elem & 127;  // Bt row r (out col / score), k in 0..127
    float v;
    if (r < NCOL) {
        v = W[k * NCOL + r];
    } else {
        int j = r - NCOL;
        v = 0.f;
        if (j < 8) {
            if (j < H) {
                float s = 0.f;
#pragma unroll
                for (int f = 0; f < 16; ++f) s += W[k * NCOL + j * 16 + f] * as[j * 16 + f];
                v = s;
            }
        } else {
            int hh = j - 8;
            if (hh < H) {
                float s = 0.f;
#pragma unroll
                for (int f = 0; f < 16; ++f) s += W[k * NCOL + hh * 16 + f] * ad[hh * 16 + f];
                v = s;
            }
        }
    }
    split_write(Bh, Bl, r * 128 + k, v);
}

#define T1 (144 * 128)
#define T3 (80 * 128)
__global__ __launch_bounds__(256) void prep_kernel(
    const float* __restrict__ W1, const float* __restrict__ W2, const float* __restrict__ W3,
    const float* __restrict__ as1, const float* __restrict__ ad1,
    const float* __restrict__ as2, const float* __restrict__ ad2,
    const float* __restrict__ as3, const float* __restrict__ ad3,
    half_t* __restrict__ B1h, half_t* __restrict__ B1l,
    half_t* __restrict__ B2h, half_t* __restrict__ B2l,
    half_t* __restrict__ B3h, half_t* __restrict__ B3l,
    int* __restrict__ gcursor, float* __restrict__ dout) {
    int id = blockIdx.x * 256 + threadIdx.x;
    if (id < T1) {
        build_bt(W1, as1, ad1, B1h, B1l, id, 128, 8);
    } else if (id < 2 * T1) {
        build_bt(W2, as2, ad2, B2h, B2l, id - T1, 128, 8);
    } else if (id < 2 * T1 + T3) {
        build_bt(W3, as3, ad3, B3h, B3l, id - 2 * T1, 64, 4);
    } else {
        int i = id - (2 * T1 + T3);
        if (i < NB) {
            gcursor[i] = 0;
        } else {
            int z = i - NB;
            if (z < ZOUT) ((float4*)dout)[z] = make_float4(0.f, 0.f, 0.f, 0.f);
        }
    }
}

// ---------------------------------------------------------------------------
// CSR build (r9-proven): bucket binning -> per-bucket fine scatter into
// bucket-slack-layout csr with per-node begin/end. Packed src*64+dloc.
// ---------------------------------------------------------------------------
__global__ __launch_bounds__(256) void bin_kernel(const int* __restrict__ A,
                                                  int* __restrict__ gcursor,
                                                  int* __restrict__ binned, int e, int n) {
    __shared__ int lcount[NB];
    __shared__ int lbase[NB];
    int chunk0 = blockIdx.x * CHUNK;
    int cend = chunk0 + CHUNK;
    if (cend > e + n) cend = e + n;
    for (int i = threadIdx.x; i < NB; i += 256) lcount[i] = 0;
    __syncthreads();
    int sreg[16], dreg[16];
#pragma unroll
    for (int l = 0; l < 16; ++l) {
        int i = chunk0 + l * 256 + threadIdx.x;
        if (i < cend) {
            if (i < e) { sreg[l] = A[i]; dreg[l] = A[e + i]; }
            else       { sreg[l] = dreg[l] = i - e; }
            atomicAdd(&lcount[dreg[l] >> BKT_SHIFT], 1);
        } else {
            dreg[l] = -1;
        }
    }
    __syncthreads();
    for (int b = threadIdx.x; b < NB; b += 256) {
        int c = lcount[b];
        lbase[b] = c ? atomicAdd(&gcursor[b], c) : 0;
        lcount[b] = 0;
    }
    __syncthreads();
#pragma unroll
    for (int l = 0; l < 16; ++l) {
        if (dreg[l] >= 0) {
            int bkt = dreg[l] >> BKT_SHIFT;
            int pos = lbase[bkt] + atomicAdd(&lcount[bkt], 1);
            if (pos < BSLACK)
                binned[(size_t)bkt * BSLACK + pos] = (sreg[l] << 6) | (dreg[l] & 63);
        }
    }
}

__global__ __launch_bounds__(256) void fine_scatter(const int* __restrict__ binned,
                                                    const int* __restrict__ gcursor,
                                                    int* __restrict__ begE,
                                                    int* __restrict__ endE,
                                                    int* __restrict__ csr) {
    __shared__ int lc[64];
    __shared__ int scur[64];
    int b = blockIdx.x;
    int node0 = b << BKT_SHIFT;
    int cnt = gcursor[b];
    if (cnt > BSLACK) cnt = BSLACK;
    const int* bp = binned + (size_t)b * BSLACK;
    if (threadIdx.x < 64) lc[threadIdx.x] = 0;
    __syncthreads();
    for (int j = threadIdx.x; j < cnt; j += 256) atomicAdd(&lc[bp[j] & 63], 1);
    __syncthreads();
    if (threadIdx.x < 64) {  // wave-parallel exclusive scan over 64 counts
        int lane = threadIdx.x;
        int c = lc[lane];
        int v = c;
#pragma unroll
        for (int off = 1; off < 64; off <<= 1) {
            int u = __shfl_up(v, off, 64);
            if (lane >= off) v += u;
        }
        int begin = b * BSLACK + v - c;  // bucket-local slack layout
        scur[lane] = begin;
        int node = node0 + lane;
        if (node < NN) {
            begE[node] = begin;
            endE[node] = begin + c;
        }
    }
    __syncthreads();
    for (int j = threadIdx.x; j < cnt; j += 256) {
        int v = bp[j];
        int pos = atomicAdd(&scur[v & 63], 1);
        csr[pos] = v >> 6;
    }
}

// ---------------------------------------------------------------------------
// Split-fp16 MFMA GEMM, LDS-staged B in fragment order (unchanged main loop).
// Epilogue writes PAIR-INTERLEAVED outputs:
//   C16[pair][node][32]  (2 heads x 16 feats adjacent -> 64 B/node/pair)
//   ss  [pair][node][2], ds[pair][node][2]
// so the aggregation pass gathers one contiguous 64 B run per edge from a
// 3.2 MB L2-resident table.
// ---------------------------------------------------------------------------
template <int NTC, int H, bool A32>
__global__ __launch_bounds__(256) void gemm_mfma(
    const float* __restrict__ X32,
    const half_t* __restrict__ Ah, const half_t* __restrict__ Al,
    const half_t* __restrict__ Bth, const half_t* __restrict__ Btl,
    half_t* __restrict__ C16, float* __restrict__ ss, float* __restrict__ ds, int M) {
    constexpr int NCOL = NTC * 16;
    constexpr int NR = NTC + 1;               // tiles incl. score tile
    constexpr int NCHUNK = NR * 256;          // 16B chunks per B array
    __shared__ __align__(16) half_t Bs[2][NR * 2048];  // 73.7 KB (NTC=8)
    int tid = threadIdx.x;
    int w = tid >> 6, lane = tid & 63;
    int m = lane & 15, q = lane >> 4;
    int row0 = blockIdx.x * 64 + w * 16;

    // cooperative fragment-ordered B load (each thread NR chunks per array)
    for (int P = tid; P < NCHUNK; P += 256) {
        int nt = P >> 8, k0 = (P >> 6) & 3, qq = (P >> 4) & 3, mm = P & 15;
        int src = (nt * 16 + mm) * 128 + qq * 8 + k0 * 32;  // half index
        *(half8_t*)&Bs[0][(size_t)P * 8] = *(const half8_t*)&Bth[src];
        *(half8_t*)&Bs[1][(size_t)P * 8] = *(const half8_t*)&Btl[src];
    }

    // A fragment (VMEM, per-wave) — overlaps the barrier
    int ar = row0 + m;
    if (ar >= M) ar = M - 1;  // clamp (stores are guarded)
    half8_t ahf[4], alf[4];
    if constexpr (A32) {
        const float* px = X32 + (size_t)ar * 128 + q * 8;
#pragma unroll
        for (int k0 = 0; k0 < 4; ++k0) {
            float4 u0 = *(const float4*)(px + k0 * 32);
            float4 u1 = *(const float4*)(px + k0 * 32 + 4);
            float uv[8] = {u0.x, u0.y, u0.z, u0.w, u1.x, u1.y, u1.z, u1.w};
#pragma unroll
            for (int j = 0; j < 8; ++j) {
                half_t h = (half_t)uv[j];
                ahf[k0][j] = h;
                alf[k0][j] = (half_t)(uv[j] - (float)h);
            }
        }
    } else {
        const half_t* pa = Ah + (size_t)ar * 128 + q * 8;
        const half_t* pl = Al + (size_t)ar * 128 + q * 8;
#pragma unroll
        for (int k0 = 0; k0 < 4; ++k0) {
            ahf[k0] = *(const half8_t*)(pa + k0 * 32);
            alf[k0] = *(const half8_t*)(pl + k0 * 32);
        }
    }

    __syncthreads();

    float4_t acc[NR];
#pragma unroll
    for (int nt = 0; nt < NR; ++nt) {
        acc[nt][0] = 0.f; acc[nt][1] = 0.f; acc[nt][2] = 0.f; acc[nt][3] = 0.f;
    }

#pragma unroll
    for (int nt = 0; nt < NR; ++nt) {
#pragma unroll
        for (int k0 = 0; k0 < 4; ++k0) {
            half8_t bh = *(const half8_t*)&Bs[0][(size_t)((nt * 4 + k0) * 64 + lane) * 8];
            half8_t bl = *(const half8_t*)&Bs[1][(size_t)((nt * 4 + k0) * 64 + lane) * 8];
            acc[nt] = __builtin_amdgcn_mfma_f32_16x16x32_f16(ahf[k0], bh, acc[nt], 0, 0, 0);
            acc[nt] = __builtin_amdgcn_mfma_f32_16x16x32_f16(ahf[k0], bl, acc[nt], 0, 0, 0);
            acc[nt] = __builtin_amdgcn_mfma_f32_16x16x32_f16(alf[k0], bh, acc[nt], 0, 0, 0);
        }
    }

    // ss/ds pair-interleaved straight from the score tile's D layout
    // (col=m, row=q*4+r):  ss[(pair*M + row)*2 + hh]
#pragma unroll
    for (int r = 0; r < 4; ++r) {
        int grow = row0 + q * 4 + r;
        if (grow < M) {
            float v = acc[NTC][r];
            if (m < H) ss[((size_t)(m >> 1) * M + grow) * 2 + (m & 1)] = v;
            else if (m >= 8 && m < 8 + H) ds[((size_t)((m - 8) >> 1) * M + grow) * 2 + ((m - 8) & 1)] = v;
        }
    }

    // C16 pair-interleaved store: reuse the B LDS region as transpose bounce.
    // cs rows padded +8 halfs so the per-head column read is <=4-way banked.
    __syncthreads();
    constexpr int LDC = NCOL + 8;
    half_t* cs = (half_t*)Bs;  // [4 waves][16 rows][LDC] strips, per-wave disjoint
#pragma unroll
    for (int nt = 0; nt < NTC; ++nt)
#pragma unroll
        for (int r = 0; r < 4; ++r)
            cs[(size_t)(w * 16 + q * 4 + r) * LDC + nt * 16 + m] = (half_t)acc[nt][r];
    // copy out: per pass one PAIR; the wave covers 16 rows x 32 B = 512 B
    // contiguous in the [pair][node][32] layout.
    int head2 = lane >> 5, rr = (lane >> 1) & 15, hf8 = lane & 1;
    int growc = row0 + rr;
#pragma unroll
    for (int p = 0; p < NTC / 2; ++p) {
        int head = p * 2 + head2;
        half8_t v = *(const half8_t*)&cs[(size_t)(w * 16 + rr) * LDC + head * 16 + hf8 * 8];
        if (growc < M)
            *(half8_t*)(C16 + ((size_t)p * M + growc) * 32 + head2 * 16 + hf8 * 8) = v;
    }
}

// ---------------------------------------------------------------------------
// XCD-pinned head-pair aggregation. pair = (blockIdx&7)/XPP: with the
// empirical round-robin block->XCD mapping each XCD works on ONE pair for the
// whole dispatch, so that pair's 3.2 MB table stays L2-resident (perf-only
// assumption; degrades gracefully if mapping differs). Per node: 16 lanes =
// 4 edge streams x (2 heads x 2 halves); per edge the 4 lanes read one
// contiguous 64 B run of C16[pair][src][32] (full-line requests, round-0
// request efficiency) + one 8 B ss run.
// Layers 1-2: hi/lo fp16 outputs node-major. Layer 3 (MEAN): the 2 pair
// blocks atomically add per-head-normalized halves into zeroed d_out.
// ---------------------------------------------------------------------------
template <int NPAIR, bool MEAN, bool RELU>
__global__ __launch_bounds__(256) void aggregate_px(
    const half_t* __restrict__ h, const float* __restrict__ ss,
    const float* __restrict__ dsa, const int* __restrict__ csr,
    const int* __restrict__ begE, const int* __restrict__ endE,
    const float* __restrict__ bias, half_t* __restrict__ outh,
    half_t* __restrict__ outl, float* __restrict__ out, int n, int groups) {
    constexpr int XPP = 8 / NPAIR;        // XCDs per pair
    int b = blockIdx.x;
    int xcd = b & 7;
    int pair = xcd / XPP;
    int g = (b >> 3) * XPP + (xcd % XPP);
    if (g >= groups) return;
    int lane = threadIdx.x & 63;
    int node = g * 16 + ((threadIdx.x >> 6) << 2) + (lane >> 4);
    int ql = lane & 15;
    int stream = ql >> 2, hh = (ql >> 1) & 1, half = ql & 1;
    const half_t* ht = h + (size_t)pair * n * 32 + hh * 16 + half * 8;
    const float* ssh = ss + (size_t)pair * n * 2 + hh;
    float dsc = dsa[((size_t)pair * n + node) * 2 + hh];
    int begin = begE[node], end = endE[node];

    float ssum = 0.f;
    float acc[8];
#pragma unroll
    for (int k = 0; k < 8; ++k) acc[k] = 0.f;

    int j = begin + stream;               // stream's edges: j, j+4, j+8, ...
    for (; j + 12 < end; j += 16) {       // 4 edges per iteration
        int s0 = __builtin_nontemporal_load(&csr[j]);
        int s1 = __builtin_nontemporal_load(&csr[j + 4]);
        int s2 = __builtin_nontemporal_load(&csr[j + 8]);
        int s3 = __builtin_nontemporal_load(&csr[j + 12]);
        float e0 = ssh[(size_t)s0 * 2], e1 = ssh[(size_t)s1 * 2];
        float e2 = ssh[(size_t)s2 * 2], e3 = ssh[(size_t)s3 * 2];
        half8_t t0 = *(const half8_t*)(ht + (size_t)s0 * 32);
        half8_t t1 = *(const half8_t*)(ht + (size_t)s1 * 32);
        half8_t t2 = *(const half8_t*)(ht + (size_t)s2 * 32);
        half8_t t3 = *(const half8_t*)(ht + (size_t)s3 * 32);
        e0 += dsc; e1 += dsc; e2 += dsc; e3 += dsc;
        e0 = fmaxf(e0, 0.2f * e0); e1 = fmaxf(e1, 0.2f * e1);   // leaky relu
        e2 = fmaxf(e2, 0.2f * e2); e3 = fmaxf(e3, 0.2f * e3);
        float x0 = __expf(e0), x1 = __expf(e1), x2 = __expf(e2), x3 = __expf(e3);
        ssum += (x0 + x1) + (x2 + x3);
#pragma unroll
        for (int k = 0; k < 8; ++k) {
            acc[k] = fmaf(x0, (float)t0[k], acc[k]);
            acc[k] = fmaf(x1, (float)t1[k], acc[k]);
            acc[k] = fmaf(x2, (float)t2[k], acc[k]);
            acc[k] = fmaf(x3, (float)t3[k], acc[k]);
        }
    }
    for (; j + 4 < end; j += 8) {         // 2 edges
        int s0 = __builtin_nontemporal_load(&csr[j]);
        int s1 = __builtin_nontemporal_load(&csr[j + 4]);
        float e0 = ssh[(size_t)s0 * 2], e1 = ssh[(size_t)s1 * 2];
        half8_t t0 = *(const half8_t*)(ht + (size_t)s0 * 32);
        half8_t t1 = *(const half8_t*)(ht + (size_t)s1 * 32);
        e0 += dsc; e1 += dsc;
        e0 = fmaxf(e0, 0.2f * e0); e1 = fmaxf(e1, 0.2f * e1);
        float x0 = __expf(e0), x1 = __expf(e1);
        ssum += x0 + x1;
#pragma unroll
        for (int k = 0; k < 8; ++k) {
            acc[k] = fmaf(x0, (float)t0[k], acc[k]);
            acc[k] = fmaf(x1, (float)t1[k], acc[k]);
        }
    }
    for (; j < end; j += 4) {             // tail: at most one edge per stream
        int s0 = __builtin_nontemporal_load(&csr[j]);
        float e0 = ssh[(size_t)s0 * 2] + dsc;
        half8_t t0 = *(const half8_t*)(ht + (size_t)s0 * 32);
        e0 = fmaxf(e0, 0.2f * e0);
        float x0 = __expf(e0);
        ssum += x0;
#pragma unroll
        for (int k = 0; k < 8; ++k) acc[k] = fmaf(x0, (float)t0[k], acc[k]);
    }

    // reduce across the 4 streams (ql bits 2-3); (hh,half) preserved
    ssum += __shfl_xor(ssum, 4, 64);
    ssum += __shfl_xor(ssum, 8, 64);
#pragma unroll
    for (int k = 0; k < 8; ++k) {
        acc[k] += __shfl_xor(acc[k], 4, 64);
        acc[k] += __shfl_xor(acc[k], 8, 64);
    }
    float inv = 1.f / (ssum + 1e-16f);

    if constexpr (!MEAN) {
        if (ql < 4) {  // one lane per (hh,half): 4 x 16 B = 64 B per node
            half8_t hv, lv;
#pragma unroll
            for (int k = 0; k < 8; ++k) {
                float t = acc[k] * inv + bias[pair * 32 + hh * 16 + half * 8 + k];
                if (RELU) t = fmaxf(t, 0.f);
                hv[k] = (half_t)t;
                lv[k] = (half_t)(t - (float)hv[k]);
            }
            size_t off = (size_t)node * (NPAIR * 32) + pair * 32 + hh * 16 + half * 8;
            *(half8_t*)(outh + off) = hv;
            *(half8_t*)(outl + off) = lv;
        }
    } else {
        // per-head normalize, mean over the pair's 2 heads, atomic into d_out.
        // bias*0.5 added by both pair blocks -> full bias.
        float v[8];
#pragma unroll
        for (int k = 0; k < 8; ++k) {
            float t = acc[k] * inv;
            t += __shfl_xor(t, 2, 64);    // add the other head of this pair
            v[k] = t * 0.25f + bias[half * 8 + k] * 0.5f;
        }
        if (ql < 2) {
#pragma unroll
            for (int k = 0; k < 8; ++k)
                atomicAdd(out + (size_t)node * 16 + half * 8 + k, v[k]);
        }
    }
}

// ---------------------------------------------------------------------------
extern "C" void kernel_launch(void* const* d_in, const int* in_sizes, int n_in,
                              void* d_out, int out_size, void* d_ws, size_t ws_size,
                              hipStream_t stream) {
    const float* X  = (const float*)d_in[0];
    const int*   A  = (const int*)d_in[1];
    const float* W1 = (const float*)d_in[2];
    const float* as1 = (const float*)d_in[3];
    const float* ad1 = (const float*)d_in[4];
    const float* b1  = (const float*)d_in[5];
    const float* W2 = (const float*)d_in[6];
    const float* as2 = (const float*)d_in[7];
    const float* ad2 = (const float*)d_in[8];
    const float* b2  = (const float*)d_in[9];
    const float* W3 = (const float*)d_in[10];
    const float* as3 = (const float*)d_in[11];
    const float* ad3 = (const float*)d_in[12];
    const float* b3  = (const float*)d_in[13];

    const int N = NN, E = EE;
    const int Etot = E + N;

    char* p = (char*)d_ws;
    auto take = [&](size_t bytes) {
        char* r = p;
        p += (bytes + 255) & ~(size_t)255;
        return (void*)r;
    };
    half_t* C16   = (half_t*)take((size_t)N * 128 * 2);  // pair-interleaved h tables
    half_t* Ph    = (half_t*)take((size_t)N * 128 * 2);  // layer-1/2 activations hi
    half_t* Pl    = (half_t*)take((size_t)N * 128 * 2);  // layer-1/2 activations lo
    float* ssb    = (float*)take((size_t)N * 8 * 4);     // pair-interleaved [P][N][2]
    float* dsb    = (float*)take((size_t)N * 8 * 4);     // pair-interleaved [P][N][2]
    int* begE     = (int*)take((size_t)N * 4);
    int* endE     = (int*)take((size_t)N * 4);
    int* gcursor  = (int*)take((size_t)NB * 4);
    int* csr      = (int*)take((size_t)NB * BSLACK * 4); // slack layout, 8.4 MB
    half_t* B1h   = (half_t*)take(144 * 128 * 2);
    half_t* B1l   = (half_t*)take(144 * 128 * 2);
    half_t* B2h   = (half_t*)take(144 * 128 * 2);
    half_t* B2l   = (half_t*)take(144 * 128 * 2);
    half_t* B3h   = (half_t*)take(80 * 128 * 2);
    half_t* B3l   = (half_t*)take(80 * 128 * 2);
    // binned slack regions alias Ph (8.4 MB < 12.8 MB); Ph is dead until the
    // layer-1 aggregate, which runs strictly after fine_scatter.
    int* binned   = (int*)Ph;

    // --- prep (W^T hi/lo + folded score cols, gcursor zero, d_out zero) ---
    const int prepTotal = 2 * T1 + T3 + NB + ZOUT;
    prep_kernel<<<(prepTotal + 255) / 256, 256, 0, stream>>>(
        W1, W2, W3, as1, ad1, as2, ad2, as3, ad3,
        B1h, B1l, B2h, B2l, B3h, B3l, gcursor, (float*)d_out);
    bin_kernel<<<(Etot + CHUNK - 1) / CHUNK, 256, 0, stream>>>(A, gcursor, binned, E, N);
    fine_scatter<<<NB, 256, 0, stream>>>(binned, gcursor, begE, endE, csr);

    const int gemmRows = (N + 63) / 64;
    const int aggGroups = (N + 15) / 16;                 // 3125 (3125*16 == 50000)
    const int grid12 = 8 * ((aggGroups + 1) / 2);        // NPAIR=4: 2 XCDs/pair
    const int grid3  = 8 * ((aggGroups + 3) / 4);        // NPAIR=2: 4 XCDs/pair

    // --- layer 1 (A = X fp32, split in-kernel) ---
    gemm_mfma<8, 8, true><<<gemmRows, 256, 0, stream>>>(X, nullptr, nullptr,
                                                        B1h, B1l, C16, ssb, dsb, N);
    aggregate_px<4, false, true><<<grid12, 256, 0, stream>>>(
        C16, ssb, dsb, csr, begE, endE, b1, Ph, Pl, nullptr, N, aggGroups);

    // --- layer 2 (agg writes back over Ph/Pl, dead after gemm2 reads them) ---
    gemm_mfma<8, 8, false><<<gemmRows, 256, 0, stream>>>(nullptr, Ph, Pl,
                                                         B2h, B2l, C16, ssb, dsb, N);
    aggregate_px<4, false, true><<<grid12, 256, 0, stream>>>(
        C16, ssb, dsb, csr, begE, endE, b2, Ph, Pl, nullptr, N, aggGroups);

    // --- layer 3 (H=4, per-head softmax, mean over heads via pair atomics) ---
    gemm_mfma<4, 4, false><<<gemmRows, 256, 0, stream>>>(nullptr, Ph, Pl,
                                                         B3h, B3l, C16, ssb, dsb, N);
    aggregate_px<2, true, false><<<grid3, 256, 0, stream>>>(
        C16, ssb, dsb, csr, begE, endE, b3, nullptr, nullptr, (float*)d_out, N, aggGroups);
}

// Round 3
// 352.229 us; speedup vs baseline: 1.6832x; 1.3178x over previous
//
#include <hip/hip_runtime.h>
#include <hip/hip_bf16.h>

// Problem constants (from reference)
#define NN 50000
#define EE 1600000
#define DIN 128

#define BKT_SHIFT 6                       // 64 nodes per bucket
#define NB ((NN + 63) >> 6)               // 782 buckets
#define BSLACK 2688                       // slack slots per bucket (mean 2110, +12.5 sigma)
#define CHUNK 4096                        // edges per binning workgroup (16/thread)

typedef _Float16 half_t;
typedef __attribute__((ext_vector_type(2))) _Float16 half2_t;
typedef __attribute__((ext_vector_type(4))) _Float16 half4_t;
typedef __attribute__((ext_vector_type(8))) _Float16 half8_t;
typedef __attribute__((ext_vector_type(4))) float float4_t;

// v_fma_mix_f32: acc(f32) += x(f32) * f16half(t). Kills the separate
// v_cvt_f32_f16 per gathered feature (half the inner-loop VALU).
#define FMIX_LO(a, x, t) \
    asm("v_fma_mix_f32 %0, %1, %2, %0 op_sel:[0,0,0] op_sel_hi:[0,1,0]" \
        : "+v"(a) : "v"(x), "v"(t))
#define FMIX_HI(a, x, t) \
    asm("v_fma_mix_f32 %0, %1, %2, %0 op_sel:[0,1,0] op_sel_hi:[0,1,0]" \
        : "+v"(a) : "v"(x), "v"(t))

template <int FPL>
__device__ __forceinline__ void mix_acc(float* acc, float x, const unsigned int* t) {
#pragma unroll
    for (int r = 0; r < FPL / 2; ++r) {
        FMIX_LO(acc[2 * r], x, t[r]);
        FMIX_HI(acc[2 * r + 1], x, t[r]);
    }
}

// ---------------------------------------------------------------------------
// prep: build extended B^T hi/lo for each layer (W^T plus a 16-wide folded
// score tile: cols j<8 = ss head j, j>=8 = ds head j-8), and zero gcursor.
// ---------------------------------------------------------------------------
__device__ __forceinline__ void split_write(half_t* __restrict__ bh, half_t* __restrict__ bl,
                                            int idx, float v) {
    half_t h = (half_t)v;
    bh[idx] = h;
    bl[idx] = (half_t)(v - (float)h);
}

__device__ __forceinline__ void build_bt(const float* __restrict__ W,
                                         const float* __restrict__ as,
                                         const float* __restrict__ ad,
                                         half_t* __restrict__ Bh, half_t* __restrict__ Bl,
                                         int elem, int NCOL, int H) {
    int r = elem >> 7, k = elem & 127;  // Bt row r (out col / score), k in 0..127
    float v;
    if (r < NCOL) {
        v = W[k * NCOL + r];
    } else {
        int j = r - NCOL;
        v = 0.f;
        if (j < 8) {
            if (j < H) {
                float s = 0.f;
#pragma unroll
                for (int f = 0; f < 16; ++f) s += W[k * NCOL + j * 16 + f] * as[j * 16 + f];
                v = s;
            }
        } else {
            int hh = j - 8;
            if (hh < H) {
                float s = 0.f;
#pragma unroll
                for (int f = 0; f < 16; ++f) s += W[k * NCOL + hh * 16 + f] * ad[hh * 16 + f];
                v = s;
            }
        }
    }
    split_write(Bh, Bl, r * 128 + k, v);
}

#define T1 (144 * 128)
#define T3 (80 * 128)
__global__ __launch_bounds__(256) void prep_kernel(
    const float* __restrict__ W1, const float* __restrict__ W2, const float* __restrict__ W3,
    const float* __restrict__ as1, const float* __restrict__ ad1,
    const float* __restrict__ as2, const float* __restrict__ ad2,
    const float* __restrict__ as3, const float* __restrict__ ad3,
    half_t* __restrict__ B1h, half_t* __restrict__ B1l,
    half_t* __restrict__ B2h, half_t* __restrict__ B2l,
    half_t* __restrict__ B3h, half_t* __restrict__ B3l,
    int* __restrict__ gcursor) {
    int id = blockIdx.x * 256 + threadIdx.x;
    if (id < T1) {
        build_bt(W1, as1, ad1, B1h, B1l, id, 128, 8);
    } else if (id < 2 * T1) {
        build_bt(W2, as2, ad2, B2h, B2l, id - T1, 128, 8);
    } else if (id < 2 * T1 + T3) {
        build_bt(W3, as3, ad3, B3h, B3l, id - 2 * T1, 64, 4);
    } else {
        int i = id - (2 * T1 + T3);
        if (i < NB) gcursor[i] = 0;
    }
}

// ---------------------------------------------------------------------------
// CSR build (r9-proven): bucket binning -> per-bucket fine scatter into
// bucket-slack-layout csr with per-node begin/end. Packed src*64+dloc.
// ---------------------------------------------------------------------------
__global__ __launch_bounds__(256) void bin_kernel(const int* __restrict__ A,
                                                  int* __restrict__ gcursor,
                                                  int* __restrict__ binned, int e, int n) {
    __shared__ int lcount[NB];
    __shared__ int lbase[NB];
    int chunk0 = blockIdx.x * CHUNK;
    int cend = chunk0 + CHUNK;
    if (cend > e + n) cend = e + n;
    for (int i = threadIdx.x; i < NB; i += 256) lcount[i] = 0;
    __syncthreads();
    int sreg[16], dreg[16];
#pragma unroll
    for (int l = 0; l < 16; ++l) {
        int i = chunk0 + l * 256 + threadIdx.x;
        if (i < cend) {
            if (i < e) { sreg[l] = A[i]; dreg[l] = A[e + i]; }
            else       { sreg[l] = dreg[l] = i - e; }
            atomicAdd(&lcount[dreg[l] >> BKT_SHIFT], 1);
        } else {
            dreg[l] = -1;
        }
    }
    __syncthreads();
    for (int b = threadIdx.x; b < NB; b += 256) {
        int c = lcount[b];
        lbase[b] = c ? atomicAdd(&gcursor[b], c) : 0;
        lcount[b] = 0;
    }
    __syncthreads();
#pragma unroll
    for (int l = 0; l < 16; ++l) {
        if (dreg[l] >= 0) {
            int bkt = dreg[l] >> BKT_SHIFT;
            int pos = lbase[bkt] + atomicAdd(&lcount[bkt], 1);
            if (pos < BSLACK)
                binned[(size_t)bkt * BSLACK + pos] = (sreg[l] << 6) | (dreg[l] & 63);
        }
    }
}

__global__ __launch_bounds__(256) void fine_scatter(const int* __restrict__ binned,
                                                    const int* __restrict__ gcursor,
                                                    int* __restrict__ begE,
                                                    int* __restrict__ endE,
                                                    int* __restrict__ csr) {
    __shared__ int lc[64];
    __shared__ int scur[64];
    int b = blockIdx.x;
    int node0 = b << BKT_SHIFT;
    int cnt = gcursor[b];
    if (cnt > BSLACK) cnt = BSLACK;
    const int* bp = binned + (size_t)b * BSLACK;
    if (threadIdx.x < 64) lc[threadIdx.x] = 0;
    __syncthreads();
    for (int j = threadIdx.x; j < cnt; j += 256) atomicAdd(&lc[bp[j] & 63], 1);
    __syncthreads();
    if (threadIdx.x < 64) {  // wave-parallel exclusive scan over 64 counts
        int lane = threadIdx.x;
        int c = lc[lane];
        int v = c;
#pragma unroll
        for (int off = 1; off < 64; off <<= 1) {
            int u = __shfl_up(v, off, 64);
            if (lane >= off) v += u;
        }
        int begin = b * BSLACK + v - c;  // bucket-local slack layout
        scur[lane] = begin;
        int node = node0 + lane;
        if (node < NN) {
            begE[node] = begin;
            endE[node] = begin + c;
        }
    }
    __syncthreads();
    for (int j = threadIdx.x; j < cnt; j += 256) {
        int v = bp[j];
        int pos = atomicAdd(&scur[v & 63], 1);
        csr[pos] = v >> 6;
    }
}

// ---------------------------------------------------------------------------
// Split-fp16 MFMA GEMM, LDS-staged B in fragment order (round-0 proven).
// Node-major outputs: C16[node][HF], ss/ds[node][H].
// ---------------------------------------------------------------------------
template <int NTC, int H, bool A32>
__global__ __launch_bounds__(256) void gemm_mfma(
    const float* __restrict__ X32,
    const half_t* __restrict__ Ah, const half_t* __restrict__ Al,
    const half_t* __restrict__ Bth, const half_t* __restrict__ Btl,
    half_t* __restrict__ C16, float* __restrict__ ss, float* __restrict__ ds, int M) {
    constexpr int NCOL = NTC * 16;
    constexpr int NR = NTC + 1;               // tiles incl. score tile
    constexpr int NCHUNK = NR * 256;          // 16B chunks per B array
    __shared__ __align__(16) half_t Bs[2][NR * 2048];  // 73.7 KB (NTC=8)
    int tid = threadIdx.x;
    int w = tid >> 6, lane = tid & 63;
    int m = lane & 15, q = lane >> 4;
    int row0 = blockIdx.x * 64 + w * 16;

    // cooperative fragment-ordered B load (each thread NR chunks per array)
    for (int P = tid; P < NCHUNK; P += 256) {
        int nt = P >> 8, k0 = (P >> 6) & 3, qq = (P >> 4) & 3, mm = P & 15;
        int src = (nt * 16 + mm) * 128 + qq * 8 + k0 * 32;  // half index
        *(half8_t*)&Bs[0][(size_t)P * 8] = *(const half8_t*)&Bth[src];
        *(half8_t*)&Bs[1][(size_t)P * 8] = *(const half8_t*)&Btl[src];
    }

    // A fragment (VMEM, per-wave) — overlaps the barrier
    int ar = row0 + m;
    if (ar >= M) ar = M - 1;  // clamp (stores are guarded)
    half8_t ahf[4], alf[4];
    if constexpr (A32) {
        const float* px = X32 + (size_t)ar * 128 + q * 8;
#pragma unroll
        for (int k0 = 0; k0 < 4; ++k0) {
            float4 u0 = *(const float4*)(px + k0 * 32);
            float4 u1 = *(const float4*)(px + k0 * 32 + 4);
            float uv[8] = {u0.x, u0.y, u0.z, u0.w, u1.x, u1.y, u1.z, u1.w};
#pragma unroll
            for (int j = 0; j < 8; ++j) {
                half_t h = (half_t)uv[j];
                ahf[k0][j] = h;
                alf[k0][j] = (half_t)(uv[j] - (float)h);
            }
        }
    } else {
        const half_t* pa = Ah + (size_t)ar * 128 + q * 8;
        const half_t* pl = Al + (size_t)ar * 128 + q * 8;
#pragma unroll
        for (int k0 = 0; k0 < 4; ++k0) {
            ahf[k0] = *(const half8_t*)(pa + k0 * 32);
            alf[k0] = *(const half8_t*)(pl + k0 * 32);
        }
    }

    __syncthreads();

    float4_t acc[NR];
#pragma unroll
    for (int nt = 0; nt < NR; ++nt) {
        acc[nt][0] = 0.f; acc[nt][1] = 0.f; acc[nt][2] = 0.f; acc[nt][3] = 0.f;
    }

#pragma unroll
    for (int nt = 0; nt < NR; ++nt) {
#pragma unroll
        for (int k0 = 0; k0 < 4; ++k0) {
            half8_t bh = *(const half8_t*)&Bs[0][(size_t)((nt * 4 + k0) * 64 + lane) * 8];
            half8_t bl = *(const half8_t*)&Bs[1][(size_t)((nt * 4 + k0) * 64 + lane) * 8];
            acc[nt] = __builtin_amdgcn_mfma_f32_16x16x32_f16(ahf[k0], bh, acc[nt], 0, 0, 0);
            acc[nt] = __builtin_amdgcn_mfma_f32_16x16x32_f16(ahf[k0], bl, acc[nt], 0, 0, 0);
            acc[nt] = __builtin_amdgcn_mfma_f32_16x16x32_f16(alf[k0], bh, acc[nt], 0, 0, 0);
        }
    }

    // ss/ds straight from the score tile's D layout (col=m, row=q*4+r)
#pragma unroll
    for (int r = 0; r < 4; ++r) {
        int grow = row0 + q * 4 + r;
        if (grow < M) {
            float v = acc[NTC][r];
            if (m < H) ss[(size_t)grow * H + m] = v;
            else if (m >= 8 && m < 8 + H) ds[(size_t)grow * H + (m - 8)] = v;
        }
    }

    // C16 store: reuse the B LDS region as transpose bounce (barrier first)
    __syncthreads();
    half_t* cs = (half_t*)Bs;  // [4][16][NCOL] strips, per-wave disjoint
#pragma unroll
    for (int nt = 0; nt < NTC; ++nt)
#pragma unroll
        for (int r = 0; r < 4; ++r)
            cs[(size_t)(w * 16 + q * 4 + r) * NCOL + nt * 16 + m] = (half_t)acc[nt][r];
    constexpr int LPR = NCOL / 8;   // lanes per row (16-B chunks)
    constexpr int RPP = 64 / LPR;   // rows per pass
    constexpr int NP = 16 / RPP;    // passes
    int rid = lane / LPR, cid = lane % LPR;
#pragma unroll
    for (int p = 0; p < NP; ++p) {
        int r = p * RPP + rid;
        int grow = row0 + r;
        half8_t v = *(const half8_t*)&cs[(size_t)(w * 16 + r) * NCOL + cid * 8];
        if (grow < M) *(half8_t*)(C16 + (size_t)grow * NCOL + cid * 8) = v;
    }
}

// ---------------------------------------------------------------------------
// Quarter-wave aggregation, round-0 structure + two upgrades:
//   (1) 8-edge-deep unroll per stream: all 8 csr, then all 8 ss + 8 row
//       gathers issued before any consumption -> ~4x per-wave MLP.
//   (2) v_fma_mix_f32 accumulate: f16 convert folded into the fp32 FMA,
//       halving inner-loop VALU (was cvt+fmac per feature).
// ---------------------------------------------------------------------------
template <int H, int F, bool MEAN, bool RELU>
__global__ __launch_bounds__(256) void aggregate_qw(
    const half_t* __restrict__ h, const float* __restrict__ ss, const float* __restrict__ dsc_arr,
    const int* __restrict__ csr, const int* __restrict__ begE, const int* __restrict__ endE,
    const float* __restrict__ bias, half_t* __restrict__ outh, half_t* __restrict__ outl,
    float* __restrict__ out, int n) {
    constexpr int HF = H * F;
    constexpr int FPL = HF / 16;  // 8 (HF=128) or 4 (HF=64)
    int wave = blockIdx.x * (blockDim.x >> 6) + (threadIdx.x >> 6);
    int lane = threadIdx.x & 63;
    if (wave >= n) return;
    int q = lane >> 4, ql = lane & 15;
    int hf = ql * FPL;
    int hh = hf / F;
    float dsc = dsc_arr[wave * H + hh];
    int begin = begE[wave], end = endE[wave];

    float ssum = 0.f;
    float acc[FPL];
#pragma unroll
    for (int k = 0; k < FPL; ++k) acc[k] = 0.f;

    int j = begin + q;  // this quarter's edge stream: j, j+4, j+8, ...
    for (; j + 28 < end; j += 32) {  // 8 edges per iteration, all loads up front
        int s[8];
#pragma unroll
        for (int u = 0; u < 8; ++u) s[u] = csr[j + 4 * u];
        float e[8];
        unsigned int t[8][FPL / 2];
#pragma unroll
        for (int u = 0; u < 8; ++u) {
            e[u] = ss[s[u] * H + hh];
            const half_t* hp = h + (size_t)s[u] * HF + hf;
            if constexpr (FPL == 8) {
                uint4 v = *(const uint4*)hp;
                t[u][0] = v.x; t[u][1] = v.y; t[u][2] = v.z; t[u][3] = v.w;
            } else {
                uint2 v = *(const uint2*)hp;
                t[u][0] = v.x; t[u][1] = v.y;
            }
        }
#pragma unroll
        for (int u = 0; u < 8; ++u) {
            float ev = e[u] + dsc;
            ev = fmaxf(ev, 0.2f * ev);
            float x = __expf(ev);
            ssum += x;
            mix_acc<FPL>(acc, x, t[u]);
        }
    }
    for (; j + 12 < end; j += 16) {  // 4-edge tail block
        int s[4];
#pragma unroll
        for (int u = 0; u < 4; ++u) s[u] = csr[j + 4 * u];
        float e[4];
        unsigned int t[4][FPL / 2];
#pragma unroll
        for (int u = 0; u < 4; ++u) {
            e[u] = ss[s[u] * H + hh];
            const half_t* hp = h + (size_t)s[u] * HF + hf;
            if constexpr (FPL == 8) {
                uint4 v = *(const uint4*)hp;
                t[u][0] = v.x; t[u][1] = v.y; t[u][2] = v.z; t[u][3] = v.w;
            } else {
                uint2 v = *(const uint2*)hp;
                t[u][0] = v.x; t[u][1] = v.y;
            }
        }
#pragma unroll
        for (int u = 0; u < 4; ++u) {
            float ev = e[u] + dsc;
            ev = fmaxf(ev, 0.2f * ev);
            float x = __expf(ev);
            ssum += x;
            mix_acc<FPL>(acc, x, t[u]);
        }
    }
    for (; j < end; j += 4) {  // singles: at most 3 per stream
        int s0 = csr[j];
        float ev = ss[s0 * H + hh] + dsc;
        const half_t* hp = h + (size_t)s0 * HF + hf;
        unsigned int t[FPL / 2];
        if constexpr (FPL == 8) {
            uint4 v = *(const uint4*)hp;
            t[0] = v.x; t[1] = v.y; t[2] = v.z; t[3] = v.w;
        } else {
            uint2 v = *(const uint2*)hp;
            t[0] = v.x; t[1] = v.y;
        }
        ev = fmaxf(ev, 0.2f * ev);
        float x = __expf(ev);
        ssum += x;
        mix_acc<FPL>(acc, x, t);
    }

    // merge the four quarters (lanes l, l^16, l^32, l^48 hold same features)
    ssum += __shfl_xor(ssum, 16, 64);
    ssum += __shfl_xor(ssum, 32, 64);
#pragma unroll
    for (int k = 0; k < FPL; ++k) {
        acc[k] += __shfl_xor(acc[k], 16, 64);
        acc[k] += __shfl_xor(acc[k], 32, 64);
    }

    float inv = 1.f / (ssum + 1e-16f);
    if constexpr (!MEAN) {
        // 128 outputs by 32 lanes; emit hi/lo fp16 split for the next MFMA GEMM
        if (lane < 32) {
            int k0 = (lane >> 4) * 4;  // 0 or 4
            int f = (lane & 15) * FPL + k0;
            float v[4];
#pragma unroll
            for (int i = 0; i < 4; ++i) {
                v[i] = acc[k0 + i] * inv + bias[f + i];
                if (RELU) v[i] = fmaxf(v[i], 0.f);
            }
            half4_t hh4, ll4;
#pragma unroll
            for (int i = 0; i < 4; ++i) {
                hh4[i] = (half_t)v[i];
                ll4[i] = (half_t)(v[i] - (float)hh4[i]);
            }
            *(half4_t*)(outh + (size_t)wave * HF + f) = hh4;
            *(half4_t*)(outl + (size_t)wave * HF + f) = ll4;
        }
    } else {
        // FPL == 4, H == 4: normalize per head, then mean over heads
        float val[FPL];
#pragma unroll
        for (int k = 0; k < FPL; ++k) {
            val[k] = acc[k] * inv;
            val[k] += __shfl_xor(val[k], 4, 64);
            val[k] += __shfl_xor(val[k], 8, 64);
        }
        if (lane < 4) {
            float v0 = val[0] * 0.25f + bias[lane * 4 + 0];
            float v1 = val[1] * 0.25f + bias[lane * 4 + 1];
            float v2 = val[2] * 0.25f + bias[lane * 4 + 2];
            float v3 = val[3] * 0.25f + bias[lane * 4 + 3];
            *(float4*)(out + (size_t)wave * F + lane * 4) = make_float4(v0, v1, v2, v3);
        }
    }
}

// ---------------------------------------------------------------------------
extern "C" void kernel_launch(void* const* d_in, const int* in_sizes, int n_in,
                              void* d_out, int out_size, void* d_ws, size_t ws_size,
                              hipStream_t stream) {
    const float* X  = (const float*)d_in[0];
    const int*   A  = (const int*)d_in[1];
    const float* W1 = (const float*)d_in[2];
    const float* as1 = (const float*)d_in[3];
    const float* ad1 = (const float*)d_in[4];
    const float* b1  = (const float*)d_in[5];
    const float* W2 = (const float*)d_in[6];
    const float* as2 = (const float*)d_in[7];
    const float* ad2 = (const float*)d_in[8];
    const float* b2  = (const float*)d_in[9];
    const float* W3 = (const float*)d_in[10];
    const float* as3 = (const float*)d_in[11];
    const float* ad3 = (const float*)d_in[12];
    const float* b3  = (const float*)d_in[13];

    const int N = NN, E = EE;
    const int Etot = E + N;

    char* p = (char*)d_ws;
    auto take = [&](size_t bytes) {
        char* r = p;
        p += (bytes + 255) & ~(size_t)255;
        return (void*)r;
    };
    half_t* C16   = (half_t*)take((size_t)N * 128 * 2);  // fp16 h rows (all layers)
    half_t* Ph    = (half_t*)take((size_t)N * 128 * 2);  // layer-1/2 activations hi
    half_t* Pl    = (half_t*)take((size_t)N * 128 * 2);  // layer-1/2 activations lo
    float* ssb    = (float*)take((size_t)N * 8 * 4);
    float* dsb    = (float*)take((size_t)N * 8 * 4);
    int* begE     = (int*)take((size_t)N * 4);
    int* endE     = (int*)take((size_t)N * 4);
    int* gcursor  = (int*)take((size_t)NB * 4);
    int* csr      = (int*)take((size_t)NB * BSLACK * 4);  // slack layout, 8.4 MB
    half_t* B1h   = (half_t*)take(144 * 128 * 2);
    half_t* B1l   = (half_t*)take(144 * 128 * 2);
    half_t* B2h   = (half_t*)take(144 * 128 * 2);
    half_t* B2l   = (half_t*)take(144 * 128 * 2);
    half_t* B3h   = (half_t*)take(80 * 128 * 2);
    half_t* B3l   = (half_t*)take(80 * 128 * 2);
    // binned slack regions alias Ph (8.4 MB < 12.8 MB); Ph is dead until the
    // layer-1 aggregate, which runs strictly after fine_scatter.
    int* binned   = (int*)Ph;

    // --- prep (W^T hi/lo + folded score cols, gcursor zero) + CSR build ---
    const int prepTotal = 2 * T1 + T3 + NB;
    prep_kernel<<<(prepTotal + 255) / 256, 256, 0, stream>>>(
        W1, W2, W3, as1, ad1, as2, ad2, as3, ad3,
        B1h, B1l, B2h, B2l, B3h, B3l, gcursor);
    bin_kernel<<<(Etot + CHUNK - 1) / CHUNK, 256, 0, stream>>>(A, gcursor, binned, E, N);
    fine_scatter<<<NB, 256, 0, stream>>>(binned, gcursor, begE, endE, csr);

    const int gemmRows = (N + 63) / 64;
    const int aggBlocks = (N + 3) / 4;

    // --- layer 1 (A = X fp32, split in-kernel) ---
    gemm_mfma<8, 8, true><<<gemmRows, 256, 0, stream>>>(X, nullptr, nullptr,
                                                        B1h, B1l, C16, ssb, dsb, N);
    aggregate_qw<8, 16, false, true>
        <<<aggBlocks, 256, 0, stream>>>(C16, ssb, dsb, csr, begE, endE, b1, Ph, Pl, nullptr, N);

    // --- layer 2 (agg writes back over Ph/Pl, dead after gemm2 reads them) ---
    gemm_mfma<8, 8, false><<<gemmRows, 256, 0, stream>>>(nullptr, Ph, Pl,
                                                         B2h, B2l, C16, ssb, dsb, N);
    aggregate_qw<8, 16, false, true>
        <<<aggBlocks, 256, 0, stream>>>(C16, ssb, dsb, csr, begE, endE, b2, Ph, Pl, nullptr, N);

    // --- layer 3 (H=4, mean over heads, no relu) ---
    gemm_mfma<4, 4, false><<<gemmRows, 256, 0, stream>>>(nullptr, Ph, Pl,
                                                         B3h, B3l, C16, ssb, dsb, N);
    aggregate_qw<4, 16, true, false>
        <<<aggBlocks, 256, 0, stream>>>(C16, ssb, dsb, csr, begE, endE, b3, nullptr, nullptr,
                                        (float*)d_out, N);
}